// Round 1
// baseline (554.840 us; speedup 1.0000x reference)
//
#include <hip/hip_runtime.h>
#include <hip/hip_fp16.h>

// Problem: B=32, S=2048, D=1024, H=1024
//   qp = query@W2 [B,H]; keys = values@W1 [B,S,H]; scores = tanh(qp+keys)@v [B,S]
//   w = softmax(scores); ctx = w@values [B,D]. Outputs: ctx (32768) ++ w (65536).
//
// R4: fp16 values-conversion pass ELIMINATED. k_scores reads values fp32
// directly (reg-staged cvt->fp16 into swizzled LDS); np=4 re-reads served by
// L2 via XCD-chunked block swizzle. k_prep shrinks 33184 -> 544 blocks.

typedef _Float16 v8h __attribute__((ext_vector_type(8)));
typedef float    v4f __attribute__((ext_vector_type(4)));

#define B_DIM 32
#define S_DIM 2048
#define D_DIM 1024
#define H_DIM 1024

// workspace layout (bytes) -- ~2.4 MiB
#define WS_W1T    0u                       // [H][D] fp16 = 2 MiB
#define WS_QP     2097152u                 // [B][H] fp32
#define WS_SCORES (WS_QP + 131072u)        // [B][S] fp32 (atomicAdd target)

// async global->LDS, 16B per lane; LDS dest = wave-uniform base + lane*16
__device__ __forceinline__ void gl_lds16(const _Float16* g, _Float16* l) {
    __builtin_amdgcn_global_load_lds(
        (const __attribute__((address_space(1))) void*)g,
        (__attribute__((address_space(3))) void*)l, 16, 0, 0);
}

// ---------------- K0: prep (small now) ----------------
// blocks [0,256):   qp = query @ W2  (32 b x 8 hc, 2-way K-split per block)
// blocks [256,512): W1 [D,H] -> W1T [H,D] fp16
// blocks [512,544): zero scores
__global__ void k_prep(const float* __restrict__ W1, _Float16* __restrict__ w1t,
                       const float* __restrict__ query, const float* __restrict__ W2,
                       float* __restrict__ qp, float* __restrict__ scores) {
    __shared__ float smem[64 * 65];
    int bid = blockIdx.x, tid = threadIdx.x;
    if (bid < 256) {
        // qp: block (b, hc) computes qp[b, hc*128 .. hc*128+128)
        int b = bid >> 3, hc = bid & 7;
        #pragma unroll
        for (int i = 0; i < 4; ++i)
            smem[i * 256 + tid] = query[b * D_DIM + i * 256 + tid];
        __syncthreads();
        int hh = tid & 127, half = tid >> 7;
        int h = hc * 128 + hh;
        const float* w2p = W2 + (size_t)(half * 512) * H_DIM + h;
        float acc = 0.f;
        #pragma unroll 8
        for (int d = 0; d < 512; ++d)
            acc += smem[half * 512 + d] * w2p[(size_t)d * H_DIM];
        smem[1024 + tid] = acc;
        __syncthreads();
        if (tid < 128)
            qp[b * H_DIM + hc * 128 + tid] = smem[1024 + tid] + smem[1024 + 128 + tid];
    } else if (bid < 512) {
        int j = bid - 256;
        int h0 = (j & 15) * 64, d0 = (j >> 4) * 64;
        #pragma unroll
        for (int i = 0; i < 16; ++i) {
            int idx = i * 256 + tid;
            int dd = idx >> 6, hh = idx & 63;
            smem[dd * 65 + hh] = W1[(size_t)(d0 + dd) * H_DIM + h0 + hh];
        }
        __syncthreads();
        #pragma unroll
        for (int i = 0; i < 16; ++i) {
            int idx = i * 256 + tid;
            int hh = idx >> 6, dd = idx & 63;
            w1t[(size_t)(h0 + hh) * D_DIM + d0 + dd] = (_Float16)smem[dd * 65 + hh];
        }
    } else {
        int j = bid - 512;
        size_t o = (size_t)j * 2048 + tid * 8;
        *(v4f*)(scores + o)     = (v4f){0.f, 0.f, 0.f, 0.f};
        *(v4f*)(scores + o + 4) = (v4f){0.f, 0.f, 0.f, 0.f};
    }
}

// ---------------- K1: fused scores GEMM ----------------
// grid = 2048 blocks (XCD-chunk swizzled), 256 thr (2x2 waves)
// block tile 128(m) x 256(n), wave tile 64x128 (mt=4, nt=8), BK=64.
// A (values) read fp32 from HBM, cvt->fp16, reg-staged into swizzled LDS;
// A loads for tile t+1 issued BEFORE compute of tile t (latency hidden).
// B (w1t fp16) staged via global_load_lds as before.
__global__ __launch_bounds__(256, 2) void k_scores(
        const float* __restrict__ values, const _Float16* __restrict__ w1t,
        const float* __restrict__ qp, const float* __restrict__ v,
        float* __restrict__ scores) {
    __shared__ _Float16 As[128 * 64];   // 16 KiB
    __shared__ _Float16 Bs[256 * 64];   // 32 KiB
    __shared__ float s_scores[128];

    int tid = threadIdx.x;
    int wid = tid >> 6, lane = tid & 63;
    int quad = lane >> 4, l15 = lane & 15;
    int wm = wid >> 1, wn = wid & 1;

    // XCD-chunked bijective swizzle: 2048 % 8 == 0. np-siblings (idx adjacent)
    // land on the same XCD -> A-tile fp32 re-reads are L2 hits.
    int bid = blockIdx.x;
    int idx = (bid & 7) * 256 + (bid >> 3);
    int np  = idx & 3;
    int mtb = idx >> 2;
    int b   = mtb >> 4;
    int m0  = (mtb & 15) * 128;
    int n0  = np * 256;

    if (tid < 128) s_scores[tid] = 0.f;

    // ---- A staging geometry: 4 issues x (8 rows x 8 fp32-slots) ----
    int arow  = lane >> 3;      // row within 8-row group
    int aslot = lane & 7;       // which 8-half k-slot
    const float* abase = values + ((size_t)b * S_DIM + m0) * D_DIM;
    int a_row[4], a_off[4];
    #pragma unroll
    for (int i = 0; i < 4; ++i) {
        int row  = i * 32 + wid * 8 + arow;
        a_row[i] = row;
        a_off[i] = row * 64 + (aslot ^ (row & 7)) * 8;   // swizzled LDS halves
    }

    // ---- B staging geometry ----
    int srow = lane >> 3;
    int kg   = lane & 7;

    v4f acc[4][8];
    #pragma unroll
    for (int i = 0; i < 4; ++i)
        #pragma unroll
        for (int j = 0; j < 8; ++j) acc[i][j] = (v4f){0.f, 0.f, 0.f, 0.f};

    v4f ap[8];
    // ---- prologue: stage tile 0 ----
    #pragma unroll
    for (int i = 0; i < 4; ++i) {
        const float* p = abase + (size_t)a_row[i] * D_DIM + aslot * 8;
        ap[2 * i]     = *(const v4f*)p;
        ap[2 * i + 1] = *(const v4f*)(p + 4);
    }
    #pragma unroll
    for (int i = 0; i < 8; ++i) {
        int brow = i * 32 + wid * 8;
        int row  = brow + srow;
        int kgs  = kg ^ (row & 7);
        gl_lds16(w1t + (size_t)(n0 + row) * D_DIM + kgs * 8, &Bs[brow * 64]);
    }
    #pragma unroll
    for (int i = 0; i < 4; ++i) {
        v8h h;
        #pragma unroll
        for (int j = 0; j < 4; ++j) {
            h[j]     = (_Float16)ap[2 * i][j];
            h[4 + j] = (_Float16)ap[2 * i + 1][j];
        }
        *(v8h*)(&As[a_off[i]]) = h;
    }
    __syncthreads();

    for (int kt = 0; kt < 16; ++kt) {
        // prefetch A for tile kt+1 into registers (unconditional address via
        // &15 clamp so loads can't be sunk/merged into the conditional write)
        int k1 = ((kt + 1) & 15) * 64;
        #pragma unroll
        for (int i = 0; i < 4; ++i) {
            const float* p = abase + (size_t)a_row[i] * D_DIM + k1 + aslot * 8;
            ap[2 * i]     = *(const v4f*)p;
            ap[2 * i + 1] = *(const v4f*)(p + 4);
        }
        __builtin_amdgcn_sched_barrier(0);

        // ---- compute tile kt ----
        #pragma unroll
        for (int kk = 0; kk < 2; ++kk) {
            v8h af[4], bf[8];
            #pragma unroll
            for (int mt = 0; mt < 4; ++mt) {
                int row = wm * 64 + mt * 16 + l15;
                int ph  = (kk * 4 + quad) ^ (row & 7);
                af[mt] = *(const v8h*)(&As[row * 64 + ph * 8]);
            }
            #pragma unroll
            for (int nt = 0; nt < 8; ++nt) {
                int row = wn * 128 + nt * 16 + l15;
                int ph  = (kk * 4 + quad) ^ (row & 7);
                bf[nt] = *(const v8h*)(&Bs[row * 64 + ph * 8]);
            }
            #pragma unroll
            for (int mt = 0; mt < 4; ++mt)
                #pragma unroll
                for (int nt = 0; nt < 8; ++nt)
                    acc[mt][nt] = __builtin_amdgcn_mfma_f32_16x16x32_f16(
                        af[mt], bf[nt], acc[mt][nt], 0, 0, 0);
        }
        __syncthreads();   // all waves done reading tile kt

        if (kt < 15) {
            // B first (async loads start flying), then A cvt+ds_write
            #pragma unroll
            for (int i = 0; i < 8; ++i) {
                int brow = i * 32 + wid * 8;
                int row  = brow + srow;
                int kgs  = kg ^ (row & 7);
                gl_lds16(w1t + (size_t)(n0 + row) * D_DIM + k1 + kgs * 8, &Bs[brow * 64]);
            }
            #pragma unroll
            for (int i = 0; i < 4; ++i) {
                v8h h;
                #pragma unroll
                for (int j = 0; j < 4; ++j) {
                    h[j]     = (_Float16)ap[2 * i][j];
                    h[4 + j] = (_Float16)ap[2 * i + 1][j];
                }
                *(v8h*)(&As[a_off[i]]) = h;
            }
        }
        __syncthreads();   // tile kt+1 ready
    }

    // ---- epilogue: scores = tanh(acc + qp) . v, reduced over n ----
    float qpv[8], vv[8];
    #pragma unroll
    for (int nt = 0; nt < 8; ++nt) {
        int ng = n0 + wn * 128 + nt * 16 + l15;
        qpv[nt] = qp[b * H_DIM + ng];
        vv[nt]  = v[ng];
    }
    #pragma unroll
    for (int mt = 0; mt < 4; ++mt) {
        #pragma unroll
        for (int r = 0; r < 4; ++r) {
            float s = 0.f;
            #pragma unroll
            for (int nt = 0; nt < 8; ++nt) {
                float x = acc[mt][nt][r] + qpv[nt];
                float e = __expf(2.f * x);           // tanh(x) = 1 - 2/(e^{2x}+1)
                s += (1.f - 2.f / (e + 1.f)) * vv[nt];
            }
            s += __shfl_xor(s, 1);
            s += __shfl_xor(s, 2);
            s += __shfl_xor(s, 4);
            s += __shfl_xor(s, 8);
            if (l15 == 0)
                atomicAdd(&s_scores[wm * 64 + mt * 16 + quad * 4 + r], s);
        }
    }
    __syncthreads();
    if (tid < 128) atomicAdd(&scores[(size_t)b * S_DIM + m0 + tid], s_scores[tid]);
}

// ---------------- K2: fused softmax + context ----------------
// One block per batch row b (32 blocks x 1024 thr). Softmax exact (full wout);
// ctx = sum_s w_s * values[b,s,:] over only weights > 1e-7 (winner-take-all:
// skipped mass <= 2048e-7 -> |ctx err| ~1e-3 << 8.2e-2 threshold). Reads
// values fp32 directly (L3-resident after k_scores).
__global__ __launch_bounds__(1024) void k_finish(
        const float* __restrict__ scores, const float* __restrict__ values,
        float* __restrict__ wout, float* __restrict__ ctx) {
    __shared__ float s_w[2048];
    __shared__ int   s_idx[2048];
    __shared__ float red[16];
    __shared__ float s_bcast;
    __shared__ int   s_cnt;

    int b = blockIdx.x, tid = threadIdx.x;
    int lane = tid & 63, wid = tid >> 6;

    float s0 = scores[b * S_DIM + tid];
    float s1 = scores[b * S_DIM + 1024 + tid];

    // --- row max ---
    float m = fmaxf(s0, s1);
    #pragma unroll
    for (int off = 1; off <= 32; off <<= 1) m = fmaxf(m, __shfl_xor(m, off));
    if (lane == 0) red[wid] = m;
    if (tid == 0) s_cnt = 0;
    __syncthreads();
    if (tid == 0) {
        float mm = red[0];
        #pragma unroll
        for (int i = 1; i < 16; ++i) mm = fmaxf(mm, red[i]);
        s_bcast = mm;
    }
    __syncthreads();
    float rowmax = s_bcast;

    // --- exp + row sum ---
    float e0 = __expf(s0 - rowmax);
    float e1 = __expf(s1 - rowmax);
    float sum = e0 + e1;
    #pragma unroll
    for (int off = 1; off <= 32; off <<= 1) sum += __shfl_xor(sum, off);
    if (lane == 0) red[wid] = sum;
    __syncthreads();
    if (tid == 0) {
        float ss = red[0];
        #pragma unroll
        for (int i = 1; i < 16; ++i) ss += red[i];
        s_bcast = 1.f / ss;
    }
    __syncthreads();
    float inv = s_bcast;

    float w0 = e0 * inv, w1 = e1 * inv;
    wout[b * S_DIM + tid]        = w0;
    wout[b * S_DIM + 1024 + tid] = w1;
    s_w[tid]        = w0;
    s_w[tid + 1024] = w1;

    // --- compact significant indices ---
    if (w0 > 1e-7f) { int p = atomicAdd(&s_cnt, 1); s_idx[p] = tid; }
    if (w1 > 1e-7f) { int p = atomicAdd(&s_cnt, 1); s_idx[p] = tid + 1024; }
    __syncthreads();
    int cnt = s_cnt;

    // --- context: thread tid owns column d=tid ---
    float acc = 0.f;
    const float* vb = values + (size_t)b * S_DIM * D_DIM + tid;
    for (int i = 0; i < cnt; ++i) {
        int s = s_idx[i];
        acc += s_w[s] * vb[(size_t)s * D_DIM];
    }
    ctx[b * D_DIM + tid] = acc;
}

extern "C" void kernel_launch(void* const* d_in, const int* in_sizes, int n_in,
                              void* d_out, int out_size, void* d_ws, size_t ws_size,
                              hipStream_t stream) {
    const float* query  = (const float*)d_in[0];
    const float* values = (const float*)d_in[1];
    const float* W1     = (const float*)d_in[2];
    const float* W2     = (const float*)d_in[3];
    const float* v      = (const float*)d_in[4];

    char* ws = (char*)d_ws;
    _Float16* w1t = (_Float16*)(ws + WS_W1T);
    float* qp     = (float*)(ws + WS_QP);
    float* scores = (float*)(ws + WS_SCORES);

    float* ctx  = (float*)d_out;            // [32, 1024]
    float* wout = (float*)d_out + 32768;    // [32, 2048]

    k_prep<<<dim3(544), 256, 0, stream>>>(W1, w1t, query, W2, qp, scores);
    k_scores<<<dim3(2048), 256, 0, stream>>>(values, w1t, qp, v, scores);
    k_finish<<<dim3(32), 1024, 0, stream>>>(scores, values, wout, ctx);
}